// Round 3
// baseline (189.507 us; speedup 1.0000x reference)
//
#include <hip/hip_runtime.h>

// NPZD plankton ODE: B*WK = 106496 independent trajectories, 56 Euler steps.
//
// R9: demand-side reads are 145 MB (L1 sees all; FETCH=72MB is L3 absorbing
// half) in 66 us = 3.6 B/cy/CU vs m13's proven 10.2 -> the fill path has
// ~2.8x headroom and we are CONCURRENCY-starved (occupancy ~3.5 waves/CU;
// grid 2048 = only 8 blocks/CU; in-flight window drains to zero during each
// compact+integrate stretch). R2-R8 all shared {25KB LDS, <=8 blocks/CU,
// same duty cycle} -> same 63-69 us.
// Fix: 2 half-batches (26 weeks) per block x 2 step-chunks of 28 per wave.
// Chunk = 21 f4/week (84 hours), f4-aligned; 42w+21c = 0 mod 3 keeps the
// R6-verified %3 compaction purely local. LDS 25KB -> 5.8KB ([26][28] x2),
// grid 4096 = 16 blocks/CU, VGPR <=128 -> ~16 resident waves/CU, each
// re-opening an 18-load in-flight window twice. Integrate on lanes 0..25
// (VALU floor ~9us/CU, not the wall).

typedef float f32x4 __attribute__((ext_vector_type(4)));

#define NPZD_B 2048
#define NPZD_WK 52
#define NPZD_HRS 8760
#define NPZD_WKH 26            // weeks per half-batch
#define NPZD_CS 28             // steps per chunk
#define NPZD_F4C 21            // float4 per week per chunk (84 hours)
#define NPZD_NI 546            // f4 per array per chunk = 26*21
#define NPZD_LDSW (NPZD_WKH * NPZD_CS)   // 728 words per array

__global__ __launch_bounds__(64, 4) void npzd_kernel(
    const float* __restrict__ X_in,     // (B, WK, 5, 1)
    const float* __restrict__ gf,       // (B, HRS)
    const float* __restrict__ gm,       // (B, HRS)
    const float* __restrict__ params,   // (B, 10)
    const float* __restrict__ dt_ptr,   // scalar
    float* __restrict__ out)            // (B, WK, 4, 8)
{
    __shared__ __align__(16) float lds_f[NPZD_LDSW];
    __shared__ __align__(16) float lds_m[NPZD_LDSW];

    const int bid  = blockIdx.x;
    const int b    = bid >> 1;
    const int hb   = bid & 1;           // half-batch: weeks [26*hb, 26*hb+26)
    const int lane = threadIdx.x;

    // ---- hoisted independent loads: in flight under the first staging ----
    const float dt = dt_ptr[0];   // 0.125
    const int wl = (lane < NPZD_WKH) ? lane : (NPZD_WKH - 1);   // local week
    const int wg = NPZD_WKH * hb + wl;                           // global week
    const float* xb = X_in + ((size_t)b * NPZD_WK + wg) * 5;
    const float x1 = xb[1], x2 = xb[2], x3 = xb[3], x4 = xb[4];

    const float* pp = params + (size_t)b * 10;   // block-uniform -> s_load
    const float chi   = pp[0];
    const float rho2  = pp[1] * 2.0f;
    const float gam1  = pp[2] * 0.1f;
    const float lam05 = pp[3] * 0.05f;
    const float eps1  = pp[4] * 0.1f;
    const float alp3  = pp[5] * 0.3f;
    const float bet6  = pp[6] * 0.6f;
    const float eta15 = pp[7] * 0.15f;
    const float phi4  = pp[8] * 0.4f;
    const float zet1  = pp[9] * 0.1f;
    const float rem   = 1.0f - alp3 - bet6;

    const f32x4* __restrict__ gf4 = (const f32x4*)(gf + (size_t)b * NPZD_HRS);
    const f32x4* __restrict__ gm4 = (const f32x4*)(gm + (size_t)b * NPZD_HRS);

    float N = x1, P = x2, Z = x3, D = x4;
    float oN[8], oP[8], oZ[8], oD[8];
    oN[0] = N; oP[0] = P; oZ[0] = Z; oD[0] = D;

    #pragma unroll
    for (int c = 0; c < 2; ++c) {
        // ---- stage: 546 f4 per array, 9 per lane, 18 loads in flight ----
        // flat i -> (week w = i/21, f = i%21); global f4 k = 42*wg + 21c + f.
        // i/21 = (i*49933)>>20, exact for i < 61681.
        f32x4 fv[9], mv[9];
        int ii[9];
        #pragma unroll
        for (int t = 0; t < 9; ++t) {
            int i = t * 64 + lane;
            if (i >= NPZD_NI) i = NPZD_NI - 1;   // dup load+dup write, benign
            ii[t] = i;
            const int w = (i * 49933) >> 20;     // i/21
            const int f = i - 21 * w;
            const int k = 42 * (NPZD_WKH * hb + w) + NPZD_F4C * c + f;
            fv[t] = gf4[k];
            mv[t] = gm4[k];
        }

        if (c) __syncthreads();   // chunk-0 LDS reads drained before overwrite

        // ---- compact: words with hour%3==0. 42w+21c = 0 mod 3 -> rm = f%3.
        // within-chunk step t' = (4f+e0)/3 in [0,28); dest p = 28*w + t'.
        #pragma unroll
        for (int t = 0; t < 9; ++t) {
            const int i = ii[t];
            const int w = (i * 49933) >> 20;
            const int f = i - 21 * w;
            const float fe[4] = {fv[t].x, fv[t].y, fv[t].z, fv[t].w};
            const float me[4] = {mv[t].x, mv[t].y, mv[t].z, mv[t].w};
            const int rm = f % 3;
            const int e0 = (rm == 0) ? 0 : (3 - rm);
            const int tp = (4 * f + e0) / 3;
            const int p  = NPZD_CS * w + tp;
            lds_f[p] = fe[e0];
            lds_m[p] = me[e0];
            if (rm == 0) {               // second multiple of 3 (e=3)
                lds_f[p + 1] = fe[3];
                lds_m[p + 1] = me[3];
            }
        }
        __syncthreads();

        // ---- integrate 28 steps: lanes 0..25, one trajectory each ----
        if (lane < NPZD_WKH) {
            const float* lf = lds_f + wl * NPZD_CS;
            const float* lm = lds_m + wl * NPZD_CS;
            #pragma unroll
            for (int g = 0; g < 7; ++g) {
                // one aligned ds_read_b128 per array per 4 steps
                const f32x4 f4 = *(const f32x4*)(lf + 4 * g);
                const f32x4 m4 = *(const f32x4*)(lm + 4 * g);
                const float fs[4] = {f4.x, f4.y, f4.z, f4.w};
                const float ms[4] = {m4.x, m4.y, m4.z, m4.w};
                #pragma unroll
                for (int q = 0; q < 4; ++q) {
                    const float ft = fs[q], mt = ms[q];
                    const float Pc = fmaxf(0.01f, P);
                    const float Zc = fmaxf(0.01f, Z);
                    const float gN = N * __builtin_amdgcn_rcpf(chi + N);
                    const float zg = rho2 * (1.0f - __expf(-lam05 * Pc)) * Zc;
                    const float up = gN * ft * Pc;
                    const float Nn = N + dt * (-up + alp3 * zg + eps1 * P + gam1 * Z + phi4 * D + mt * (8.0f - N));
                    const float Pn = P + dt * (up - zg - eps1 * P - eta15 * P - mt * P);
                    const float Zn = Z + dt * (bet6 * zg - gam1 * Z - mt * Z);
                    const float Dn = D + dt * (eta15 * P + rem * zg - phi4 * D - zet1 * D - mt * D);
                    N = Nn; P = Pn; Z = Zn; D = Dn;
                }
                const int g14 = 7 * c + g;
                if (g14 & 1) {   // after steps 7,15,...,55
                    const int co = (g14 >> 1) + 1;
                    oN[co] = N; oP[co] = P; oZ[co] = Z; oD[co] = D;
                }
            }
        }
        // loop back: next chunk's global loads issue immediately; the
        // pre-compact __syncthreads() orders them vs this chunk's reads.
    }

    // ---- output: (b, wg, state, 8) -> 32 contiguous floats/trajectory ----
    if (lane >= NPZD_WKH) return;
    f32x4* o4 = (f32x4*)(out + ((size_t)b * NPZD_WK + wg) * 32);
    o4[0] = (f32x4){oN[0], oN[1], oN[2], oN[3]};
    o4[1] = (f32x4){oN[4], oN[5], oN[6], oN[7]};
    o4[2] = (f32x4){oP[0], oP[1], oP[2], oP[3]};
    o4[3] = (f32x4){oP[4], oP[5], oP[6], oP[7]};
    o4[4] = (f32x4){oZ[0], oZ[1], oZ[2], oZ[3]};
    o4[5] = (f32x4){oZ[4], oZ[5], oZ[6], oZ[7]};
    o4[6] = (f32x4){oD[0], oD[1], oD[2], oD[3]};
    o4[7] = (f32x4){oD[4], oD[5], oD[6], oD[7]};
}

extern "C" void kernel_launch(void* const* d_in, const int* in_sizes, int n_in,
                              void* d_out, int out_size, void* d_ws, size_t ws_size,
                              hipStream_t stream) {
    const float* X_in   = (const float*)d_in[0];
    const float* gf     = (const float*)d_in[1];
    const float* gm     = (const float*)d_in[2];
    const float* params = (const float*)d_in[3];
    const float* dt_ptr = (const float*)d_in[4];
    float* out = (float*)d_out;

    npzd_kernel<<<NPZD_B * 2, 64, 0, stream>>>(X_in, gf, gm, params, dt_ptr, out);
}